// Round 7
// baseline (250.358 us; speedup 1.0000x reference)
//
#include <hip/hip_runtime.h>

#define NPIX (128 * 128)
#define CH 64
#define RMID 16
#define KK 9
#define TOTPIX (8 * NPIX)        // 131072

// ---------------- K1: conv1 + PReLU -> t_ws ----------------
// 2 threads per pixel: layer L handles channels [32L, 32L+32); partials
// combined through LDS; thread stores t rows [8L, 8L+8). 1024 blocks ->
// 16 waves/CU (2x round 6). t_ws layout [r][G] -> coalesced.
__global__ __launch_bounds__(256, 6) void conv1_kernel(
    const float* __restrict__ x,
    const float* __restrict__ w1,
    const float* __restrict__ b1,
    const float* __restrict__ prelu_a,
    float* __restrict__ t_ws)
{
    __shared__ float pl[2][128][17];     // [layer][px][r], stride 17

    const int px    = threadIdx.x & 127;
    const int layer = threadIdx.x >> 7;  // wave-pair uniform

    const int G  = blockIdx.x * 128 + px;    // pixel id 0..131071
    const int bq = G >> 14;
    const int p  = G & (NPIX - 1);

    const float* xp = x + (size_t)bq * CH * NPIX + (size_t)(32 * layer) * NPIX + p;

    float xv[32];
#pragma unroll
    for (int c = 0; c < 32; ++c) xv[c] = xp[(size_t)c * NPIX];   // all loads in flight

    float t[RMID];
#pragma unroll
    for (int r = 0; r < RMID; ++r) t[r] = (layer == 0) ? b1[r] : 0.f;

#pragma unroll
    for (int c = 0; c < 32; ++c) {
#pragma unroll
        for (int r = 0; r < RMID; ++r)
            t[r] = fmaf(w1[r * CH + 32 * layer + c], xv[c], t[r]);  // uniform -> s_load
    }
#pragma unroll
    for (int r = 0; r < RMID; ++r) pl[layer][px][r] = t[r];
    __syncthreads();

    const float a  = prelu_a[0];
    const int   r0 = 8 * layer;
#pragma unroll
    for (int r = 0; r < 8; ++r) {
        const float v = pl[0][px][r0 + r] + pl[1][px][r0 + r];
        t_ws[(r0 + r) * TOTPIX + G] = (v >= 0.f) ? v : a * v;
    }
}

// ---------------- K2: conv2 (weight gen) + involution ----------------
// XCD-pinned 1D grid: bq=L&7, gq=(L>>3)&7, strip=L>>6 (2 rows x 128 px).
// The block's 8 planes x 4 rows (strip + halo) are staged into a
// zero-guarded LDS tile (rows of 130 floats: [0]/[129] guards, halo rows
// zeroed) -> taps are ds_reads with immediate offsets, NO masks/clamps,
// no vmem latency in the inner loop.
#define STR 130                   // LDS row stride (floats)
#define PLSZ (4 * STR)            // 520 floats per staged plane
__global__ __launch_bounds__(256, 6) void invol_kernel(
    const float* __restrict__ x,
    const float* __restrict__ t_ws,
    const float* __restrict__ w2,
    const float* __restrict__ b2,
    float* __restrict__ out)
{
    __shared__ float sx[8 * PLSZ];        // 16640 B

    const int px   = threadIdx.x & 127;
    const int rsub = threadIdx.x >> 7;    // 0..1

    const int L     = blockIdx.x;         // 0..4095
    const int bq    = L & 7;              // batch == XCD pin
    const int gq    = (L >> 3) & 7;       // group-quad (consecutive on one XCD)
    const int strip = L >> 6;             // row-pair

    const int hq = 2 * strip + rsub;
    const int p  = hq * 128 + px;

    // t fragment: issue early (drains together with staging loads)
    const int G = (bq << 14) + p;
    float tr[RMID];
#pragma unroll
    for (int r = 0; r < RMID; ++r) tr[r] = t_ws[r * TOTPIX + G];

    // column guard zeros (64 slots)
    if (threadIdx.x < 64) {
        const int gpl  = threadIdx.x >> 3;
        const int grow = (threadIdx.x >> 1) & 3;
        const int side = threadIdx.x & 1;
        sx[gpl * PLSZ + grow * STR + side * (STR - 1)] = 0.f;
    }

    // stage 8 planes x 4 rows (halo rows -> 0). 16 iters x 2 half-blocks.
    const float* xq = x + (size_t)bq * CH * NPIX + (size_t)(8 * gq) * NPIX;
#pragma unroll
    for (int j = 0; j < 16; ++j) {
        const int pair = 2 * j + rsub;        // 0..31
        const int spl  = pair >> 2;           // staged plane 0..7
        const int srow = pair & 3;            // tile row 0..3
        const int gr   = 2 * strip - 1 + srow;
        const bool ok  = (unsigned)gr < 128u;
        const float v  = ok ? xq[(size_t)spl * NPIX + gr * 128 + px] : 0.f;
        sx[spl * PLSZ + srow * STR + 1 + px] = v;
    }
    __syncthreads();

    // per-lane LDS base (bytes); taps = base + immediate offsets
    const int lbase = 4 * (rsub * STR + px);
    const char* obc = (char*)(out + (size_t)bq * CH * NPIX + (size_t)(8 * gq) * NPIX);
    const int   pb  = 4 * p;

#pragma unroll 2
    for (int gi = 0; gi < 4; ++gi) {
        const int g = 4 * gq + gi;                       // block-uniform
        const float* s0 = (const float*)((const char*)sx + lbase) + (2 * gi) * PLSZ;
        const float* s1 = s0 + PLSZ;

        // -- 18 taps from LDS (immediate offsets i*STR + j) --
        float p0[KK], p1[KK];
#pragma unroll
        for (int i = 0; i < 3; ++i) {
#pragma unroll
            for (int j = 0; j < 3; ++j) {
                const int k = i * 3 + j;
                p0[k] = s0[i * STR + j];
                p1[k] = s1[i * STR + j];
            }
        }

        // -- conv2: 9 weights from tr[16] --
        float wg[KK];
#pragma unroll
        for (int k = 0; k < KK; ++k) {
            float acc = b2[g * KK + k];
            const float* w2r = w2 + (g * KK + k) * RMID;  // uniform -> s_load
#pragma unroll
            for (int r = 0; r < RMID; ++r)
                acc = fmaf(w2r[r], tr[r], acc);
            wg[k] = acc;
        }

        // -- combine + store (no masks: guards/halo are zero) --
        float o0 = 0.f, o1 = 0.f;
#pragma unroll
        for (int k = 0; k < KK; ++k) {
            o0 = fmaf(wg[k], p0[k], o0);
            o1 = fmaf(wg[k], p1[k], o1);
        }
        *(float*)(obc + (size_t)(2 * gi)     * NPIX * 4 + pb) = o0;
        *(float*)(obc + (size_t)(2 * gi + 1) * NPIX * 4 + pb) = o1;
    }
}

extern "C" void kernel_launch(void* const* d_in, const int* in_sizes, int n_in,
                              void* d_out, int out_size, void* d_ws, size_t ws_size,
                              hipStream_t stream)
{
    const float* x  = (const float*)d_in[0];
    const float* w1 = (const float*)d_in[1];
    const float* b1 = (const float*)d_in[2];
    const float* pa = (const float*)d_in[3];
    const float* w2 = (const float*)d_in[4];
    const float* b2 = (const float*)d_in[5];
    float* out  = (float*)d_out;
    float* t_ws = (float*)d_ws;              // 16 * 131072 * 4 B = 8.4 MB

    hipLaunchKernelGGL(conv1_kernel, dim3(TOTPIX / 128), dim3(256), 0, stream,
                       x, w1, b1, pa, t_ws);
    hipLaunchKernelGGL(invol_kernel, dim3(8 * 8 * 64), dim3(256), 0, stream,
                       x, t_ws, w2, b2, out);
}

// Round 8
// 129.996 us; speedup vs baseline: 1.9259x; 1.9259x over previous
//
#include <hip/hip_runtime.h>

#define NPIX (128 * 128)
#define CH 64
#define RMID 16
#define KK 9
#define TOTPIX (8 * NPIX)        // 131072

// ---------------- K1: conv1 + PReLU -> t_ws ----------------
// 2 threads per pixel: layer L handles channels [32L, 32L+32); partials
// combined via LDS; thread stores t rows [8L, 8L+8). 1024 blocks -> 16
// waves/CU. NO min-waves bound: live set (xv[32]+t[16]) must stay in
// registers — capping VGPRs spills to scratch (round 7: 111 MB WRITE, 164 us).
__global__ __launch_bounds__(256) void conv1_kernel(
    const float* __restrict__ x,
    const float* __restrict__ w1,
    const float* __restrict__ b1,
    const float* __restrict__ prelu_a,
    float* __restrict__ t_ws)
{
    __shared__ float pl[2][128][17];     // [layer][px][r], stride 17

    const int px    = threadIdx.x & 127;
    const int layer = threadIdx.x >> 7;  // wave-pair uniform

    const int G  = blockIdx.x * 128 + px;    // pixel id 0..131071
    const int bq = G >> 14;
    const int p  = G & (NPIX - 1);

    const float* xp = x + (size_t)bq * CH * NPIX + (size_t)(32 * layer) * NPIX + p;

    float xv[32];
#pragma unroll
    for (int c = 0; c < 32; ++c) xv[c] = xp[(size_t)c * NPIX];   // all loads in flight

    float t[RMID];
#pragma unroll
    for (int r = 0; r < RMID; ++r) t[r] = (layer == 0) ? b1[r] : 0.f;

#pragma unroll
    for (int c = 0; c < 32; ++c) {
#pragma unroll
        for (int r = 0; r < RMID; ++r)
            t[r] = fmaf(w1[r * CH + 32 * layer + c], xv[c], t[r]);  // uniform -> s_load
    }
#pragma unroll
    for (int r = 0; r < RMID; ++r) pl[layer][px][r] = t[r];
    __syncthreads();

    const float a  = prelu_a[0];
    const int   r0 = 8 * layer;
#pragma unroll
    for (int r = 0; r < 8; ++r) {
        const float v = pl[0][px][r0 + r] + pl[1][px][r0 + r];
        t_ws[(r0 + r) * TOTPIX + G] = (v >= 0.f) ? v : a * v;
    }
}

// ---------------- K2: conv2 (weight gen) + involution ----------------
// Round-6 structure (best so far: FETCH 38 MB clean) with the spill removed.
// XCD-pinned 1D grid: bq=L&7 (block->XCD ~ L%8), gq=(L>>3)&7 fastest (the 8
// group-quad slices of a strip are consecutive blocks on one XCD -> t-strip
// fetched once, hit 7x in L2), strip=L>>6. 256 thr = 2 rows x 128 px.
// Groups 4gq..4gq+3 block-uniform -> scalar plane bases, immediate row
// offsets for interior rows. NO min-waves bound (live set ~70 VGPR).
__global__ __launch_bounds__(256) void invol_kernel(
    const float* __restrict__ x,
    const float* __restrict__ t_ws,
    const float* __restrict__ w2,
    const float* __restrict__ b2,
    float* __restrict__ out)
{
    const int px   = threadIdx.x & 127;
    const int rsub = threadIdx.x >> 7;          // 0..1

    const int L     = blockIdx.x;               // 0..4095
    const int bq    = L & 7;                    // batch == XCD pin
    const int gq    = (L >> 3) & 7;             // group-quad (fastest per XCD)
    const int strip = L >> 6;                   // 0..63 row-pair

    const int hq = 2 * strip + rsub;
    const int p  = hq * 128 + px;

    // t fragment: 16 coalesced loads (L2-resident after swizzle)
    const int G = (bq << 14) + p;
    float tr[RMID];
#pragma unroll
    for (int r = 0; r < RMID; ++r) tr[r] = t_ws[r * TOTPIX + G];

    // per-lane clamped column byte-offsets + masks
    const int   pb   = 4 * p;
    const int   cneg = (px > 0)   ? pb - 4 : pb;
    const int   cpos = (px < 127) ? pb + 4 : pb;
    const float mneg = (px > 0)   ? 1.f : 0.f;
    const float mpos = (px < 127) ? 1.f : 0.f;

    // row offsets (wave-uniform)
    const int   ro0 = (hq > 0)   ? -512 : 0;
    const int   ro2 = (hq < 127) ?  512 : 0;
    const float rm0 = (hq > 0)   ? 1.f : 0.f;
    const float rm2 = (hq < 127) ? 1.f : 0.f;

    const char* xbc = (const char*)(x   + (size_t)bq * CH * NPIX);
    char*       obc = (char*)      (out + (size_t)bq * CH * NPIX);

#pragma unroll 2
    for (int gi = 0; gi < 4; ++gi) {
        const int g = 4 * gq + gi;                        // block-uniform
        const char* c0 = xbc + (size_t)(2 * g) * NPIX * 4;
        const char* c1 = c0 + NPIX * 4;

        // -- 18 stencil loads, batched --
        float p0[KK], p1[KK];
#pragma unroll
        for (int i = 0; i < 3; ++i) {
            const int ro = (i == 0) ? ro0 : (i == 2) ? ro2 : 0;
#pragma unroll
            for (int j = 0; j < 3; ++j) {
                const int k    = i * 3 + j;
                const int voff = (j == 0) ? cneg : (j == 2) ? cpos : pb;
                p0[k] = *(const float*)(c0 + (size_t)(voff + ro));
                p1[k] = *(const float*)(c1 + (size_t)(voff + ro));
            }
        }

        // -- conv2: 9 weights from tr[16] (covers the load latency) --
        float wg[KK];
#pragma unroll
        for (int k = 0; k < KK; ++k) {
            float acc = b2[g * KK + k];
            const float* w2r = w2 + (g * KK + k) * RMID;   // uniform -> s_load
#pragma unroll
            for (int r = 0; r < RMID; ++r)
                acc = fmaf(w2r[r], tr[r], acc);
            wg[k] = acc;
        }
        // fold border masks
        wg[0] *= mneg * rm0;  wg[1] *= rm0;  wg[2] *= mpos * rm0;
        wg[3] *= mneg;                       wg[5] *= mpos;
        wg[6] *= mneg * rm2;  wg[7] *= rm2;  wg[8] *= mpos * rm2;

        // -- combine + nontemporal store (out never re-read) --
        float o0 = 0.f, o1 = 0.f;
#pragma unroll
        for (int k = 0; k < KK; ++k) {
            o0 = fmaf(wg[k], p0[k], o0);
            o1 = fmaf(wg[k], p1[k], o1);
        }
        __builtin_nontemporal_store(o0, (float*)(obc + (size_t)(2 * g)     * NPIX * 4 + pb));
        __builtin_nontemporal_store(o1, (float*)(obc + (size_t)(2 * g + 1) * NPIX * 4 + pb));
    }
}

extern "C" void kernel_launch(void* const* d_in, const int* in_sizes, int n_in,
                              void* d_out, int out_size, void* d_ws, size_t ws_size,
                              hipStream_t stream)
{
    const float* x  = (const float*)d_in[0];
    const float* w1 = (const float*)d_in[1];
    const float* b1 = (const float*)d_in[2];
    const float* pa = (const float*)d_in[3];
    const float* w2 = (const float*)d_in[4];
    const float* b2 = (const float*)d_in[5];
    float* out  = (float*)d_out;
    float* t_ws = (float*)d_ws;              // 16 * 131072 * 4 B = 8.4 MB

    hipLaunchKernelGGL(conv1_kernel, dim3(TOTPIX / 128), dim3(256), 0, stream,
                       x, w1, b1, pa, t_ws);
    hipLaunchKernelGGL(invol_kernel, dim3(8 * 8 * 64), dim3(256), 0, stream,
                       x, t_ws, w2, b2, out);
}